// Round 6
// baseline (284.350 us; speedup 1.0000x reference)
//
#include <hip/hip_runtime.h>
#include <math.h>

#define EPSF 1e-10f
#define INV128 0.0078125f
#define C128 0.08838834764831845f   // np.float32(1/sqrt(128))

typedef float f2 __attribute__((ext_vector_type(2)));

__device__ __forceinline__ f2 fma2(f2 a, f2 b, f2 c) {
#if __has_builtin(__builtin_elementwise_fma)
    return __builtin_elementwise_fma(a, b, c);
#else
    f2 r; r.x = fmaf(a.x, b.x, c.x); r.y = fmaf(a.y, b.y, c.y); return r;
#endif
}

// ---------------- cross-lane primitives ------------------------------------

template<int CTRL>
__device__ __forceinline__ float fdpp(float v) {
    return __builtin_bit_cast(float,
        __builtin_amdgcn_update_dpp(0, __builtin_bit_cast(int, v), CTRL, 0xF, 0xF, true));
}
template<int PAT>
__device__ __forceinline__ float fswz(float v) {
    return __builtin_bit_cast(float,
        __builtin_amdgcn_ds_swizzle(__builtin_bit_cast(int, v), PAT));
}
__device__ __forceinline__ float pl32(float v, bool lower) {
#if __has_builtin(__builtin_amdgcn_permlane32_swap)
    auto r = __builtin_amdgcn_permlane32_swap(
        __builtin_bit_cast(unsigned, v), __builtin_bit_cast(unsigned, v), false, false);
    return __builtin_bit_cast(float, lower ? r[1] : r[0]);
#else
    return __shfl_xor(v, 32, 64);
#endif
}

// partner value at lane^D; DPP=false -> __shfl_xor (proven fallback)
template<bool DPP, int D>
__device__ __forceinline__ float partner(float v, bool lower) {
    if constexpr (!DPP)        { return __shfl_xor(v, D, 64); }
    else if constexpr (D == 1) { return fdpp<0xB1>(v); }     // quad_perm xor1
    else if constexpr (D == 2) { return fdpp<0x4E>(v); }     // quad_perm xor2
    else if constexpr (D == 4) { return fswz<0x101F>(v); }   // ds_swizzle xor4
    else if constexpr (D == 8) { return fdpp<0x128>(v); }    // row_ror:8 == xor8
    else if constexpr (D == 16){ return fswz<0x401F>(v); }   // ds_swizzle xor16
    else                       { return pl32(v, lower); }
}
template<bool DPP, int D>
__device__ __forceinline__ f2 partner2(f2 v, bool lower) {
    f2 r; r.x = partner<DPP, D>(v.x, lower); r.y = partner<DPP, D>(v.y, lower);
    return r;
}

template<bool DPP>
__device__ __forceinline__ float wave_sum64(float v, bool lower) {
    v += partner<DPP, 1>(v, lower);
    v += partner<DPP, 2>(v, lower);
    v += partner<DPP, 4>(v, lower);
    v += partner<DPP, 8>(v, lower);
    v += partner<DPP, 16>(v, lower);
    v += partner<DPP, 32>(v, lower);
    return v;
}

struct SignsP { f2 s[6]; bool lower; };

// FWHT over 128 elems; lane l holds v=(e[2l], e[2l+1]). Per-half arithmetic
// is bitwise identical to the scalar round-5 version (pk_fma = 2x IEEE fma).
template<bool DPP, bool SCALE>
__device__ __forceinline__ void fwht128(f2& v, const SignsP& S) {
    f2 w; w.x = v.x + v.y; w.y = v.x - v.y; v = w;     // dist 1 (in-lane)
    v = fma2(S.s[0], v, partner2<DPP, 1>(v, S.lower));
    v = fma2(S.s[1], v, partner2<DPP, 2>(v, S.lower));
    v = fma2(S.s[2], v, partner2<DPP, 4>(v, S.lower));
    v = fma2(S.s[3], v, partner2<DPP, 8>(v, S.lower));
    v = fma2(S.s[4], v, partner2<DPP, 16>(v, S.lower));
    v = fma2(S.s[5], v, partner2<DPP, 32>(v, S.lower));
    if constexpr (SCALE) { v = v * C128; }
}

// Self-check: every DPP primitive bitwise vs __shfl_xor; wave-uniform verdict.
__device__ __forceinline__ bool dpp_ok(int lane) {
    const bool lower = (lane & 32) == 0;
    const float tv = __int_as_float(0x3f800000 + lane * 1024);
    bool ok = true;
    ok = ok && (__float_as_uint(partner<true, 1>(tv, lower)) == __float_as_uint(__shfl_xor(tv, 1, 64)));
    ok = ok && (__float_as_uint(partner<true, 2>(tv, lower)) == __float_as_uint(__shfl_xor(tv, 2, 64)));
    ok = ok && (__float_as_uint(partner<true, 4>(tv, lower)) == __float_as_uint(__shfl_xor(tv, 4, 64)));
    ok = ok && (__float_as_uint(partner<true, 8>(tv, lower)) == __float_as_uint(__shfl_xor(tv, 8, 64)));
    ok = ok && (__float_as_uint(partner<true, 16>(tv, lower)) == __float_as_uint(__shfl_xor(tv, 16, 64)));
    ok = ok && (__float_as_uint(partner<true, 32>(tv, lower)) == __float_as_uint(__shfl_xor(tv, 32, 64)));
    return __all((int)ok) != 0;
}

// ---------------------------------------------------------------------------
// Setup: Lloyd-Max, 1 wave, register-resident, shfl neighbor exchange.
// Per-boundary f64 expressions are TOKEN-IDENTICAL to the round-5 (passing)
// version; only the storage/communication changed (bitwise-same results).
// Lane l owns levels 2l,2l+1 and boundaries 2l (and 2l+1 for l<63).
// ws layout (floats): [256..767] float4 tbl[128]{bnd,cb,cb_next,0} |
//                     [768..1791] int lut[1024]
// ---------------------------------------------------------------------------
__global__ __launch_bounds__(64) void lloyd_setup_kernel(float* __restrict__ ws) {
    const int l = threadIdx.x;   // 0..63
    __shared__ float sbnd[128];

    double lv0 = -4.0 + (8.0 / 127.0) * (double)(2 * l);
    double lv1 = (2 * l + 1 == 127) ? 4.0 : (-4.0 + (8.0 / 127.0) * (double)(2 * l + 1));

    const double inv_sqrt2pi = 0.39894228040143267794;
    const double inv_sqrt2   = 0.70710678118654752440;
    const double pdf_end = exp(-0.5 * 30.0 * 30.0) * inv_sqrt2pi;
    const double cdf_m30 = 0.5 * (1.0 + erf(-30.0 * inv_sqrt2));
    const double cdf_p30 = 0.5 * (1.0 + erf( 30.0 * inv_sqrt2));

#pragma unroll 1
    for (int it = 0; it < 200; ++it) {
        const double lv0n = __shfl_down(lv0, 1, 64);   // lv[2l+2] (lane63: unused)
        // boundary 2l (between lv[2l], lv[2l+1])
        double t = 0.5 * (lv0 + lv1);
        t = fmin(fmax(t, -30.0), 30.0);
        const double p0 = exp(-0.5 * t * t) * inv_sqrt2pi;
        const double c0 = 0.5 * (1.0 + erf(t * inv_sqrt2));
        // boundary 2l+1 (between lv[2l+1], lv[2l+2]); lane63: no such boundary
        double t1 = 0.5 * (lv1 + lv0n);
        t1 = fmin(fmax(t1, -30.0), 30.0);
        const double p1 = exp(-0.5 * t1 * t1) * inv_sqrt2pi;
        const double c1 = 0.5 * (1.0 + erf(t1 * inv_sqrt2));
        // boundary 2l-1 from lane l-1
        double plo0 = __shfl_up(p1, 1, 64);
        double clo0 = __shfl_up(c1, 1, 64);
        if (l == 0) { plo0 = pdf_end; clo0 = cdf_m30; }
        const double phi1 = (l == 63) ? pdf_end : p1;
        const double chi1 = (l == 63) ? cdf_p30 : c1;
        lv0 = (plo0 - p0) / fmax(c0 - clo0, 1e-30);
        lv1 = (p0 - phi1) / fmax(chi1 - c0, 1e-30);
    }

    const float cb0 = (float)lv0, cb1 = (float)lv1;
    const float cb0n = __shfl_down(cb0, 1, 64);        // scb[2l+2]
    const float INF = __int_as_float(0x7f800000);
    const float nb0 = 0.5f * (cb0 + cb1);              // bnd[2l]
    const float nb1 = (l == 63) ? INF : 0.5f * (cb1 + cb0n);  // bnd[2l+1]

    float4* tbl = (float4*)(ws + 256);
    tbl[2 * l]     = make_float4(nb0, cb0, cb1, 0.0f);
    tbl[2 * l + 1] = make_float4(nb1, cb1, (l == 63) ? cb1 : cb0n, 0.0f);
    sbnd[2 * l] = nb0; sbnd[2 * l + 1] = nb1;
    __syncthreads();

    int* lut = (int*)(ws + 768);
    for (int k = 0; k < 16; ++k) {
        const int c = l * 16 + k;
        const float cl = -4.0f + (float)c * 0.0078125f;   // cell left edge
        int g = 0;
#pragma unroll
        for (int d = 64; d >= 1; d >>= 1) g += (sbnd[g + d - 1] < cl) ? d : 0;
        lut[c] = g;   // #bounds < cell_left; true idx in {g, g+1}
    }
}

// ---------------------------------------------------------------------------
// Main kernel
// ---------------------------------------------------------------------------
__device__ __forceinline__ float lm_recon(const float4* __restrict__ tbl,
                                          const int* __restrict__ lut, float v) {
    float cf = fminf(fmaxf(fmaf(v, 128.0f, 512.0f), 0.0f), 1023.0f);
    int g = lut[(int)cf];
    float4 e = tbl[g];
    return (e.x < v) ? e.z : e.y;   // searchsorted side='left'
}

template<bool DPP>
__device__ __forceinline__ void run_rows(
        const float* __restrict__ x, float* __restrict__ out,
        const float4* __restrict__ tbl, const int* __restrict__ lut,
        f2 rs0, f2 rs1, f2 qj,
        const SignsP S, int lane, int row0, int wstride, int nrows) {
    for (int row = row0; row < nrows; row += wstride) {
        const float2 xin = ((const float2*)(x + (size_t)row * 128))[lane];
        f2 v; v.x = xin.x; v.y = xin.y;

        // ---- norm, unit vector ----
        const float norm = sqrtf(wave_sum64<DPP>(v.x * v.x + v.y * v.y, S.lower));
        const float ninv = 1.0f / (norm + EPSF);
        v = v * ninv;

        // ---- rotation_fwd, per-FWHT normalized (feeds quantizer) ----
        v = v * rs0;
        fwht128<DPP, true>(v, S);
        v = v * rs1;
        fwht128<DPP, true>(v, S);

        // ---- pass 1: numerical rms + LM quantize ----
        const float rms = sqrtf(wave_sum64<DPP>(v.x * v.x + v.y * v.y, S.lower)) * C128;
        const float si  = 1.0f / (rms + EPSF);
        f2 r; r.x = lm_recon(tbl, lut, v.x * si);
        r.y = lm_recon(tbl, lut, v.y * si);

        // ---- refined gamma ----
        const float num   = wave_sum64<DPP>(v.x * r.x + v.y * r.y, S.lower);
        const float den   = wave_sum64<DPP>(r.x * r.x + r.y * r.y, S.lower) + EPSF;
        const float gamma = num / den;
        const float gi    = 1.0f / (gamma + EPSF);

        // ---- MSE-stage quantize ----
        f2 u; u.x = lm_recon(tbl, lut, v.x * gi);
        u.y = lm_recon(tbl, lut, v.y * gi);
        const f2 rc  = u * gamma;
        const f2 res = v - rc;
        const float resn = sqrtf(wave_sum64<DPP>(res.x * res.x + res.y * res.y, S.lower));

        // ==== post-quantization (ulp-safe folds) ====
        f2 p = res * qj;
        fwht128<DPP, false>(p, S);
        f2 sg; sg.x = (p.x >= 0.0f) ? 1.0f : -1.0f;
        sg.y = (p.y >= 0.0f) ? 1.0f : -1.0f;

        fwht128<DPP, false>(sg, S);               // exact integers
        const float rscale = resn * INV128;
        f2 rsc; rsc.x = rscale; rsc.y = rscale;
        f2 c = fma2(sg * qj, rsc, rc);

        fwht128<DPP, false>(c, S);
        c = c * rs1;
        fwht128<DPP, false>(c, S);
        const float fn = norm * INV128;
        c = c * rs0;
        c = c * fn;
        float2 o; o.x = c.x; o.y = c.y;
        ((float2*)(out + (size_t)row * 128))[lane] = o;
    }
}

__global__ __launch_bounds__(256) void turboquant_kernel(
        const float* __restrict__ x,
        const float* __restrict__ rot,
        const float* __restrict__ qjl,
        const float* __restrict__ ws,
        float* __restrict__ out,
        const int nrows) {
    __shared__ float4 tbl[128];
    __shared__ int lut[1024];

    const int t = threadIdx.x;
    if (t < 128) tbl[t] = ((const float4*)(ws + 256))[t];
    {
        const int* lsrc = (const int*)(ws + 768);
#pragma unroll
        for (int i = 0; i < 4; ++i) lut[t + 256 * i] = lsrc[t + 256 * i];
    }
    __syncthreads();

    const int lane = t & 63;
    const int wid  = t >> 6;

    SignsP S;
#pragma unroll
    for (int k = 0; k < 6; ++k) {
        const float s = (lane & (1 << k)) ? -1.0f : 1.0f;
        S.s[k].x = s; S.s[k].y = s;
    }
    S.lower = (lane & 32) == 0;

    const float2 r0 = ((const float2*)rot)[lane];
    const float2 r1 = ((const float2*)rot)[64 + lane];
    const float2 qq = ((const float2*)qjl)[lane];
    f2 rs0; rs0.x = r0.x; rs0.y = r0.y;
    f2 rs1; rs1.x = r1.x; rs1.y = r1.y;
    f2 qj;  qj.x  = qq.x; qj.y  = qq.y;

    const int row0    = blockIdx.x * 4 + wid;
    const int wstride = gridDim.x * 4;

    if (dpp_ok(lane)) {
        run_rows<true >(x, out, tbl, lut, rs0, rs1, qj, S, lane, row0, wstride, nrows);
    } else {
        run_rows<false>(x, out, tbl, lut, rs0, rs1, qj, S, lane, row0, wstride, nrows);
    }
}

extern "C" void kernel_launch(void* const* d_in, const int* in_sizes, int n_in,
                              void* d_out, int out_size, void* d_ws, size_t ws_size,
                              hipStream_t stream) {
    const float* x   = (const float*)d_in[0];
    const float* rot = (const float*)d_in[1];
    const float* qjl = (const float*)d_in[2];
    float* out = (float*)d_out;
    float* ws  = (float*)d_ws;

    const int nrows = in_sizes[0] >> 7;

    lloyd_setup_kernel<<<1, 64, 0, stream>>>(ws);
    turboquant_kernel<<<8192, 256, 0, stream>>>(x, rot, qjl, ws, out, nrows);
}

// Round 8
// 279.396 us; speedup vs baseline: 1.0177x; 1.0177x over previous
//
#include <hip/hip_runtime.h>
#include <math.h>

// Pin FP contraction OFF for the whole file: every a*b+c stays rounded
// mul + rounded add (numpy per-element semantics). Explicit fma builtins
// below are unaffected (used only where exact: s = +-1).
#pragma clang fp contract(off)

#define EPSF 1e-10f
#define INV128 0.0078125f
#define C128 0.08838834764831845f   // np.float32(1/sqrt(128))

typedef float f2 __attribute__((ext_vector_type(2)));

__device__ __forceinline__ f2 fma2(f2 a, f2 b, f2 c) {
#if __has_builtin(__builtin_elementwise_fma)
    return __builtin_elementwise_fma(a, b, c);
#else
    f2 r; r.x = fmaf(a.x, b.x, c.x); r.y = fmaf(a.y, b.y, c.y); return r;
#endif
}

// ---------------- cross-lane primitives (proven in rounds 5/6) -------------

template<int CTRL>
__device__ __forceinline__ float fdpp(float v) {
    return __builtin_bit_cast(float,
        __builtin_amdgcn_update_dpp(0, __builtin_bit_cast(int, v), CTRL, 0xF, 0xF, true));
}
template<int PAT>
__device__ __forceinline__ float fswz(float v) {
    return __builtin_bit_cast(float,
        __builtin_amdgcn_ds_swizzle(__builtin_bit_cast(int, v), PAT));
}
__device__ __forceinline__ float pl32(float v, bool lower) {
#if __has_builtin(__builtin_amdgcn_permlane32_swap)
    auto r = __builtin_amdgcn_permlane32_swap(
        __builtin_bit_cast(unsigned, v), __builtin_bit_cast(unsigned, v), false, false);
    return __builtin_bit_cast(float, lower ? r[1] : r[0]);
#else
    return __shfl_xor(v, 32, 64);
#endif
}

template<bool DPP, int D>
__device__ __forceinline__ float partner(float v, bool lower) {
    if constexpr (!DPP)        { return __shfl_xor(v, D, 64); }
    else if constexpr (D == 1) { return fdpp<0xB1>(v); }     // quad_perm xor1
    else if constexpr (D == 2) { return fdpp<0x4E>(v); }     // quad_perm xor2
    else if constexpr (D == 4) { return fswz<0x101F>(v); }   // ds_swizzle xor4
    else if constexpr (D == 8) { return fdpp<0x128>(v); }    // row_ror:8 == xor8
    else if constexpr (D == 16){ return fswz<0x401F>(v); }   // ds_swizzle xor16
    else                       { return pl32(v, lower); }
}
template<bool DPP, int D>
__device__ __forceinline__ f2 partner2(f2 v, bool lower) {
    f2 r; r.x = partner<DPP, D>(v.x, lower); r.y = partner<DPP, D>(v.y, lower);
    return r;
}

// dual-row wave reduction (two independent chains interleaved for ILP)
template<bool DPP>
__device__ __forceinline__ void wsum2(float& a, float& b, bool lower) {
    a += partner<DPP, 1>(a, lower);  b += partner<DPP, 1>(b, lower);
    a += partner<DPP, 2>(a, lower);  b += partner<DPP, 2>(b, lower);
    a += partner<DPP, 4>(a, lower);  b += partner<DPP, 4>(b, lower);
    a += partner<DPP, 8>(a, lower);  b += partner<DPP, 8>(b, lower);
    a += partner<DPP, 16>(a, lower); b += partner<DPP, 16>(b, lower);
    a += partner<DPP, 32>(a, lower); b += partner<DPP, 32>(b, lower);
}

struct SignsP { f2 s[6]; bool lower; };

// dual-row FWHT-128; lane l holds (e[2l], e[2l+1]) of each row.
// fma2 with s=+-1 is bitwise identical to add/sub.
template<bool DPP, bool SCALE>
__device__ __forceinline__ void fwht128x2(f2& u, f2& w, const SignsP& S) {
    { f2 t; t.x = u.x + u.y; t.y = u.x - u.y; u = t; }
    { f2 t; t.x = w.x + w.y; t.y = w.x - w.y; w = t; }
#define STG(D, K) { f2 pu = partner2<DPP, D>(u, S.lower); f2 pw = partner2<DPP, D>(w, S.lower); \
                    u = fma2(S.s[K], u, pu); w = fma2(S.s[K], w, pw); }
    STG(1, 0) STG(2, 1) STG(4, 2) STG(8, 3) STG(16, 4) STG(32, 5)
#undef STG
    if constexpr (SCALE) { u = u * C128; w = w * C128; }
}

// Self-check: every DPP primitive bitwise vs __shfl_xor; wave-uniform verdict.
__device__ __forceinline__ bool dpp_ok(int lane) {
    const bool lower = (lane & 32) == 0;
    const float tv = __int_as_float(0x3f800000 + lane * 1024);
    bool ok = true;
    ok = ok && (__float_as_uint(partner<true, 1>(tv, lower)) == __float_as_uint(__shfl_xor(tv, 1, 64)));
    ok = ok && (__float_as_uint(partner<true, 2>(tv, lower)) == __float_as_uint(__shfl_xor(tv, 2, 64)));
    ok = ok && (__float_as_uint(partner<true, 4>(tv, lower)) == __float_as_uint(__shfl_xor(tv, 4, 64)));
    ok = ok && (__float_as_uint(partner<true, 8>(tv, lower)) == __float_as_uint(__shfl_xor(tv, 8, 64)));
    ok = ok && (__float_as_uint(partner<true, 16>(tv, lower)) == __float_as_uint(__shfl_xor(tv, 16, 64)));
    ok = ok && (__float_as_uint(partner<true, 32>(tv, lower)) == __float_as_uint(__shfl_xor(tv, 32, 64)));
    return __all((int)ok) != 0;
}

// ---------------------------------------------------------------------------
// Setup: PROVEN round-4/5 128-thread Lloyd-Max (f64 shared) + LUT/tbl build.
// ws layout (floats): [0..127] cb | [128..255] bnd (+inf at 255) |
//                     [256..767] float4 tbl[128]{bnd,cb,cb_next,0} |
//                     [768..1791] int lut[1024]
// ---------------------------------------------------------------------------
__global__ __launch_bounds__(128) void lloyd_setup_kernel(float* __restrict__ ws) {
    __shared__ double lv[128];
    __shared__ double bp[127];
    __shared__ double bc[127];
    __shared__ float scb[128];
    __shared__ float sbnd[128];

    const int i = threadIdx.x;   // 0..127
    lv[i] = (i == 127) ? 4.0 : (-4.0 + (8.0 / 127.0) * (double)i);
    __syncthreads();

    const double inv_sqrt2pi = 0.39894228040143267794;
    const double inv_sqrt2   = 0.70710678118654752440;
    const double pdf_end = exp(-0.5 * 30.0 * 30.0) * inv_sqrt2pi;
    const double cdf_m30 = 0.5 * (1.0 + erf(-30.0 * inv_sqrt2));
    const double cdf_p30 = 0.5 * (1.0 + erf( 30.0 * inv_sqrt2));

    for (int it = 0; it < 200; ++it) {
        if (i < 127) {
            double t = 0.5 * (lv[i] + lv[i + 1]);
            t = fmin(fmax(t, -30.0), 30.0);
            bp[i] = exp(-0.5 * t * t) * inv_sqrt2pi;
            bc[i] = 0.5 * (1.0 + erf(t * inv_sqrt2));
        }
        __syncthreads();
        const double plo = (i == 0)   ? pdf_end : bp[i - 1];
        const double clo = (i == 0)   ? cdf_m30 : bc[i - 1];
        const double phi = (i == 127) ? pdf_end : bp[i];
        const double chi = (i == 127) ? cdf_p30 : bc[i];
        const double nl  = (plo - phi) / fmax(chi - clo, 1e-30);
        __syncthreads();
        lv[i] = nl;
        __syncthreads();
    }

    const float cf = (float)lv[i];
    ws[i] = cf;
    scb[i] = cf;
    __syncthreads();

    const float INF = __int_as_float(0x7f800000);
    const float nb = (i < 127) ? 0.5f * (scb[i] + scb[i + 1]) : INF;
    ws[128 + i] = nb;
    sbnd[i] = nb;

    float4* tbl = (float4*)(ws + 256);
    tbl[i] = make_float4(nb, scb[i], scb[(i < 127) ? i + 1 : 127], 0.0f);
    __syncthreads();

    int* lut = (int*)(ws + 768);
    for (int c = i; c < 1024; c += 128) {
        const float cl = -4.0f + (float)c * 0.0078125f;   // cell left edge
        int g = 0;
#pragma unroll
        for (int d = 64; d >= 1; d >>= 1) g += (sbnd[g + d - 1] < cl) ? d : 0;
        lut[c] = g;   // #bounds < cell_left; true idx in {g, g+1}
    }
}

// ---------------------------------------------------------------------------
// Main kernel: one wave per row-pair (row, row+half) — dual-chain ILP.
// ---------------------------------------------------------------------------
__device__ __forceinline__ float lm_recon(const float4* __restrict__ tbl,
                                          const int* __restrict__ lut, float v) {
    float cf = fminf(fmaxf(fmaf(v, 128.0f, 512.0f), 0.0f), 1023.0f);
    int g = lut[(int)cf];
    float4 e = tbl[g];
    return (e.x < v) ? e.z : e.y;   // searchsorted side='left'
}

template<bool DPP>
__device__ __forceinline__ void run2(
        const float* __restrict__ x, float* __restrict__ out,
        const float4* __restrict__ tbl, const int* __restrict__ lut,
        f2 rs0, f2 rs1, f2 qj,
        const SignsP S, int lane, int row0, int wstride, int half) {
    for (int row = row0; row < half; row += wstride) {
        const float2 xa = ((const float2*)(x + (size_t)row * 128))[lane];
        const float2 xb = ((const float2*)(x + (size_t)(row + half) * 128))[lane];
        f2 u; u.x = xa.x; u.y = xa.y;
        f2 w; w.x = xb.x; w.y = xb.y;

        // ---- norms, unit vectors (rounded mul+add, contraction pinned off) ----
        float su = u.x * u.x + u.y * u.y;
        float sw = w.x * w.x + w.y * w.y;
        wsum2<DPP>(su, sw, S.lower);
        const float nu = sqrtf(su), nw = sqrtf(sw);
        const float iu = 1.0f / (nu + EPSF), iw = 1.0f / (nw + EPSF);
        u = u * iu; w = w * iw;

        // ---- rotation_fwd, per-FWHT normalized (feeds quantizer) ----
        u = u * rs0; w = w * rs0;
        fwht128x2<DPP, true>(u, w, S);
        u = u * rs1; w = w * rs1;
        fwht128x2<DPP, true>(u, w, S);

        // ---- pass 1: numerical rms + LM quantize ----
        float r2u = u.x * u.x + u.y * u.y;
        float r2w = w.x * w.x + w.y * w.y;
        wsum2<DPP>(r2u, r2w, S.lower);
        const float rmsu = sqrtf(r2u) * C128;
        const float rmsw = sqrtf(r2w) * C128;
        const float siu = 1.0f / (rmsu + EPSF);
        const float siw = 1.0f / (rmsw + EPSF);
        f2 ru, rw;
        ru.x = lm_recon(tbl, lut, u.x * siu); ru.y = lm_recon(tbl, lut, u.y * siu);
        rw.x = lm_recon(tbl, lut, w.x * siw); rw.y = lm_recon(tbl, lut, w.y * siw);

        // ---- refined gamma ----
        float numu = u.x * ru.x + u.y * ru.y;
        float numw = w.x * rw.x + w.y * rw.y;
        float denu = ru.x * ru.x + ru.y * ru.y;
        float denw = rw.x * rw.x + rw.y * rw.y;
        wsum2<DPP>(numu, numw, S.lower);
        wsum2<DPP>(denu, denw, S.lower);
        const float gu = numu / (denu + EPSF), gw = numw / (denw + EPSF);
        const float giu = 1.0f / (gu + EPSF), giw = 1.0f / (gw + EPSF);

        // ---- MSE-stage quantize ----
        f2 qu, qw;
        qu.x = lm_recon(tbl, lut, u.x * giu); qu.y = lm_recon(tbl, lut, u.y * giu);
        qw.x = lm_recon(tbl, lut, w.x * giw); qw.y = lm_recon(tbl, lut, w.y * giw);
        const f2 rcu = qu * gu, rcw = qw * gw;   // rounded mul
        const f2 reu = u - rcu, rew = w - rcw;   // rounded sub
        float rnu = reu.x * reu.x + reu.y * reu.y;
        float rnw = rew.x * rew.x + rew.y * rew.y;
        wsum2<DPP>(rnu, rnw, S.lower);
        const float resnu = sqrtf(rnu), resnw = sqrtf(rnw);

        // ==== post-quantization (ulp-safe folds) ====
        f2 pu = reu * qj, pw = rew * qj;
        fwht128x2<DPP, false>(pu, pw, S);
        f2 sgu, sgw;
        sgu.x = (pu.x >= 0.0f) ? 1.0f : -1.0f; sgu.y = (pu.y >= 0.0f) ? 1.0f : -1.0f;
        sgw.x = (pw.x >= 0.0f) ? 1.0f : -1.0f; sgw.y = (pw.y >= 0.0f) ? 1.0f : -1.0f;
        fwht128x2<DPP, false>(sgu, sgw, S);      // exact integers
        const float rsu = resnu * INV128, rsw = resnw * INV128;
        f2 cu, cw;
        cu.x = fmaf(sgu.x * qj.x, rsu, rcu.x); cu.y = fmaf(sgu.y * qj.y, rsu, rcu.y);
        cw.x = fmaf(sgw.x * qj.x, rsw, rcw.x); cw.y = fmaf(sgw.y * qj.y, rsw, rcw.y);

        // ---- inverse rotation (folded scales) ----
        fwht128x2<DPP, false>(cu, cw, S);
        cu = cu * rs1; cw = cw * rs1;
        fwht128x2<DPP, false>(cu, cw, S);
        const float fnu = nu * INV128, fnw = nw * INV128;
        cu = cu * rs0; cw = cw * rs0;
        cu = cu * fnu; cw = cw * fnw;
        float2 ou; ou.x = cu.x; ou.y = cu.y;
        float2 ov; ov.x = cw.x; ov.y = cw.y;
        ((float2*)(out + (size_t)row * 128))[lane] = ou;
        ((float2*)(out + (size_t)(row + half) * 128))[lane] = ov;
    }
}

__global__ __launch_bounds__(256) void turboquant_kernel(
        const float* __restrict__ x,
        const float* __restrict__ rot,
        const float* __restrict__ qjl,
        const float* __restrict__ ws,
        float* __restrict__ out,
        const int nrows) {
    __shared__ float4 tbl[128];
    __shared__ int lut[1024];

    const int t = threadIdx.x;
    if (t < 128) tbl[t] = ((const float4*)(ws + 256))[t];
    {
        const int* lsrc = (const int*)(ws + 768);
#pragma unroll
        for (int i = 0; i < 4; ++i) lut[t + 256 * i] = lsrc[t + 256 * i];
    }
    __syncthreads();

    const int lane = t & 63;
    const int wid  = t >> 6;

    SignsP S;
#pragma unroll
    for (int k = 0; k < 6; ++k) {
        const float s = (lane & (1 << k)) ? -1.0f : 1.0f;
        S.s[k].x = s; S.s[k].y = s;
    }
    S.lower = (lane & 32) == 0;

    const float2 r0 = ((const float2*)rot)[lane];
    const float2 r1 = ((const float2*)rot)[64 + lane];
    const float2 qq = ((const float2*)qjl)[lane];
    f2 rs0; rs0.x = r0.x; rs0.y = r0.y;
    f2 rs1; rs1.x = r1.x; rs1.y = r1.y;
    f2 qj;  qj.x  = qq.x; qj.y  = qq.y;

    const int half    = nrows >> 1;
    const int row0    = blockIdx.x * 4 + wid;
    const int wstride = gridDim.x * 4;

    if (dpp_ok(lane)) {
        run2<true >(x, out, tbl, lut, rs0, rs1, qj, S, lane, row0, wstride, half);
    } else {
        run2<false>(x, out, tbl, lut, rs0, rs1, qj, S, lane, row0, wstride, half);
    }
}

extern "C" void kernel_launch(void* const* d_in, const int* in_sizes, int n_in,
                              void* d_out, int out_size, void* d_ws, size_t ws_size,
                              hipStream_t stream) {
    const float* x   = (const float*)d_in[0];
    const float* rot = (const float*)d_in[1];
    const float* qjl = (const float*)d_in[2];
    float* out = (float*)d_out;
    float* ws  = (float*)d_ws;

    const int nrows = in_sizes[0] >> 7;

    lloyd_setup_kernel<<<1, 128, 0, stream>>>(ws);
    turboquant_kernel<<<8192, 256, 0, stream>>>(x, rot, qjl, ws, out, nrows);
}